// Round 17
// baseline (124.076 us; speedup 1.0000x reference)
//
#include <hip/hip_runtime.h>
#include <hip/hip_bf16.h>

#define N_NODES 50000
#define IN_DIM 256
#define OUT_DIM 128
#define ODIM2 256        // mu(128) + logstd(128) concatenated
#define NEDGE 800000
#define MAX_LOGSTD 10.0f
#define CAP 64           // bucket capacity; P(Poisson(16) > 64) ~ 1e-18/node
#define FILL_BLOCKS 1563 // ceil((NEDGE/2)/256), 2 edges/thread
#define GEMM_TILES 1563  // ceil(N_NODES/32), 32-row tiles
#define NBLK 196

typedef short bf16x8 __attribute__((ext_vector_type(8)));
typedef float f32x4  __attribute__((ext_vector_type(4)));
typedef int   i32x4  __attribute__((ext_vector_type(4)));

__device__ __forceinline__ float b2f(unsigned short u) {
    union { unsigned int i; float f; } v; v.i = ((unsigned int)u) << 16; return v.f;
}
__device__ __forceinline__ unsigned short f2b(float f) {
    union { float f; unsigned int i; } v; v.f = f;
    unsigned int x = v.i;
    unsigned int r = (x + 0x7fffu + ((x >> 16) & 1u)) >> 16;
    return (unsigned short)r;
}
__device__ __forceinline__ bool edges_are_i64(const int* raw) {
    bool is64 = true;
    #pragma unroll
    for (int i = 0; i < 8; i++) if (raw[2 * i + 1] != 0) is64 = false;
    return is64;
}

// Pack concat(Wmu,Wls) [256x256] f32 -> B-fragment-ordered bf16.
__global__ void k_wconv(const float* __restrict__ Wmu, const float* __restrict__ Wls,
                        unsigned short* __restrict__ Wp) {
    int i = blockIdx.x * blockDim.x + threadIdx.x;   // 8192 threads
    int lane = i & 63;
    int kk   = (i >> 6) & 7;
    int tile = i >> 9;
    int k0 = kk * 32 + (lane >> 4) * 8;
    int n  = tile * 16 + (lane & 15);
    const float* W = (n < 128) ? (Wmu + n) : (Wls + (n - 128));
    unsigned short o[8];
    #pragma unroll
    for (int j = 0; j < 8; j++) o[j] = f2b(W[(size_t)(k0 + j) * OUT_DIM]);
    ushort4 lo = { o[0], o[1], o[2], o[3] };
    ushort4 hi = { o[4], o[5], o[6], o[7] };
    *(ushort4*)(Wp + (size_t)i * 8)     = lo;
    *(ushort4*)(Wp + (size_t)i * 8 + 4) = hi;
}

// HETEROGENEOUS kernel, roles interleaved by block parity.
// even blocks: bucket-scatter 2 edges/thread (NT stores). odd: 32-row MFMA
// tile (16KB LDS) writing UNSCALED h. launch_bounds(256,3): no spill (R16:
// VGPR 84), fill waves keep latency-hiding occupancy.
__global__ __launch_bounds__(256, 3) void k_fused(
    const int* __restrict__ raw, int* __restrict__ pos, int* __restrict__ csr,
    const float* __restrict__ x, const unsigned short* __restrict__ Wp,
    unsigned short* __restrict__ h)
{
    __shared__ unsigned short xs[32 * 256];   // 16 KB (gemm path), swizzled
    const int tid = threadIdx.x;

    if ((blockIdx.x & 1) == 0) {
        // ---- fill: 2 edges/thread, bucket csr[d*CAP + p] = s ----
        bool is64 = edges_are_i64(raw);
        int e2 = (blockIdx.x >> 1) * 256 + tid;   // edge-pair index
        if (e2 < NEDGE / 2) {
            int s0, s1, d0, d1;
            if (is64) {
                int4 sv = *(const int4*)(raw + 4 * e2);
                int4 dv = *(const int4*)(raw + 2 * NEDGE + 4 * e2);
                s0 = sv.x; s1 = sv.z; d0 = dv.x; d1 = dv.z;
            } else {
                int2 sv = *(const int2*)(raw + 2 * e2);
                int2 dv = *(const int2*)(raw + NEDGE + 2 * e2);
                s0 = sv.x; s1 = sv.y; d0 = dv.x; d1 = dv.y;
            }
            int p0 = atomicAdd(&pos[d0], 1);
            int p1 = atomicAdd(&pos[d1], 1);
            __builtin_nontemporal_store(s0, &csr[d0 * CAP + p0]);
            __builtin_nontemporal_store(s1, &csr[d1 * CAP + p1]);
        }
        return;
    }

    // ---- gemm: 32-row tile, 4 waves, B fragments register-resident ----
    const int lane = tid & 63;
    const int w    = tid >> 6;
    const int row0 = (blockIdx.x >> 1) * 32;

    bf16x8 breg[4][8];
    #pragma unroll
    for (int t = 0; t < 4; t++)
        #pragma unroll
        for (int kk = 0; kk < 8; kk++)
            breg[t][kk] = ((const bf16x8*)Wp)[((4 * w + t) * 8 + kk) * 64 + lane];

    #pragma unroll
    for (int i = 0; i < 8; i++) {
        int f   = i * 256 + tid;
        int row = f >> 6;
        int c4  = f & 63;
        int grow = row0 + row;
        float4 v = make_float4(0.f, 0.f, 0.f, 0.f);
        if (grow < N_NODES) v = *(const float4*)(x + (size_t)grow * IN_DIM + c4 * 4);
        ushort4 b = { f2b(v.x), f2b(v.y), f2b(v.z), f2b(v.w) };
        unsigned int byte = (unsigned)(row * 512 + c4 * 8);
        byte ^= (unsigned)((row & 7) << 4);
        *(ushort4*)((char*)xs + byte) = b;
    }
    __syncthreads();

    #pragma unroll
    for (int sub = 0; sub < 2; sub++) {
        const int arow = sub * 16 + (lane & 15);
        const unsigned int abase = (unsigned)(arow * 512 + (lane >> 4) * 16);
        const unsigned int axor  = (unsigned)((arow & 7) << 4);

        bf16x8 a[8];
        #pragma unroll
        for (int kk = 0; kk < 8; kk++)
            a[kk] = *(const bf16x8*)((const char*)xs + ((abase + kk * 64) ^ axor));

        f32x4 acc[4];
        #pragma unroll
        for (int t = 0; t < 4; t++) acc[t] = (f32x4){0.f, 0.f, 0.f, 0.f};

        #pragma unroll
        for (int kk = 0; kk < 8; kk++)
            #pragma unroll
            for (int t = 0; t < 4; t++)
                acc[t] = __builtin_amdgcn_mfma_f32_16x16x32_bf16(a[kk], breg[t][kk],
                                                                 acc[t], 0, 0, 0);

        // C/D layout: col=lane&15, row=(lane>>4)*4+reg. UNSCALED store.
        const int rbase = row0 + sub * 16 + (lane >> 4) * 4;
        const int cl = lane & 15;
        #pragma unroll
        for (int t = 0; t < 4; t++) {
            int col = (4 * w + t) * 16 + cl;
            #pragma unroll
            for (int r = 0; r < 4; r++) {
                int row = rbase + r;
                if (row < N_NODES)
                    h[(size_t)row * ODIM2 + col] = f2b(acc[t][r]);
            }
        }
    }
}

// Tiny: dinv[n] = rsqrt(deg+1). Removes 2 VALU ops/edge/lane from the gather.
__global__ __launch_bounds__(256) void k_dinv(const int* __restrict__ pos,
                                              float* __restrict__ dinv) {
    int idx = blockIdx.x * 256 + threadIdx.x;
    if (idx < N_NODES) dinv[idx] = rsqrtf((float)pos[idx] + 1.0f);
}

#define NTI4(p) __builtin_nontemporal_load((const i32x4*)(p))
#define FMA4(c, v) { a0 = fmaf(c, b2f((v).x), a0); a1 = fmaf(c, b2f((v).y), a1); \
                     a2 = fmaf(c, b2f((v).z), a2); a3 = fmaf(c, b2f((v).w), a3); }

// Wave-per-node pull gather, 8 edges in flight. Coefficients via dinv[] loads
// (wave-uniform broadcast, no per-lane rsqrt). out = dn*(dn*h[n] + sum c_s h[s]).
__global__ __launch_bounds__(256) void k_gather(
    const int* __restrict__ pos, const int* __restrict__ csr,
    const float* __restrict__ dinv, const unsigned short* __restrict__ hs,
    const float* __restrict__ eps, const float* __restrict__ bmu,
    const float* __restrict__ bls, float* __restrict__ z)
{
    const int tid  = threadIdx.x;
    const int n    = blockIdx.x * 4 + (tid >> 6);
    const int lane = tid & 63;
    const int deg  = pos[n];
    const float dn = dinv[n];

    // hoist streaming epilogue input (NT: don't pollute L2)
    f32x4 ep = {0.f, 0.f, 0.f, 0.f};
    if (lane < 32)
        ep = __builtin_nontemporal_load((const f32x4*)(eps + (size_t)n * OUT_DIM + lane * 4));

    float a0, a1, a2, a3;
    {   // self-loop seed: dn * h[n]  (outer dn applied at the end)
        ushort4 v = ((const ushort4*)(hs + (size_t)n * ODIM2))[lane];
        a0 = dn * b2f(v.x); a1 = dn * b2f(v.y);
        a2 = dn * b2f(v.z); a3 = dn * b2f(v.w);
    }

    const int beg = n * CAP;                       // 4-aligned by construction
    const int end = beg + deg;
    int j = beg;
    for (; j + 8 <= end; j += 8) {                 // 8 gathers in flight
        i32x4 sA = NTI4(csr + j);
        i32x4 sB = NTI4(csr + j + 4);
        float c0 = dinv[sA[0]];
        float c1 = dinv[sA[1]];
        float c2 = dinv[sA[2]];
        float c3 = dinv[sA[3]];
        float c4 = dinv[sB[0]];
        float c5 = dinv[sB[1]];
        float c6 = dinv[sB[2]];
        float c7 = dinv[sB[3]];
        ushort4 v0 = ((const ushort4*)(hs + (size_t)sA[0] * ODIM2))[lane];
        ushort4 v1 = ((const ushort4*)(hs + (size_t)sA[1] * ODIM2))[lane];
        ushort4 v2 = ((const ushort4*)(hs + (size_t)sA[2] * ODIM2))[lane];
        ushort4 v3 = ((const ushort4*)(hs + (size_t)sA[3] * ODIM2))[lane];
        ushort4 v4 = ((const ushort4*)(hs + (size_t)sB[0] * ODIM2))[lane];
        ushort4 v5 = ((const ushort4*)(hs + (size_t)sB[1] * ODIM2))[lane];
        ushort4 v6 = ((const ushort4*)(hs + (size_t)sB[2] * ODIM2))[lane];
        ushort4 v7 = ((const ushort4*)(hs + (size_t)sB[3] * ODIM2))[lane];
        FMA4(c0, v0); FMA4(c1, v1); FMA4(c2, v2); FMA4(c3, v3);
        FMA4(c4, v4); FMA4(c5, v5); FMA4(c6, v6); FMA4(c7, v7);
    }
    if (j + 4 <= end) {
        i32x4 sA = NTI4(csr + j);
        float c0 = dinv[sA[0]];
        float c1 = dinv[sA[1]];
        float c2 = dinv[sA[2]];
        float c3 = dinv[sA[3]];
        ushort4 v0 = ((const ushort4*)(hs + (size_t)sA[0] * ODIM2))[lane];
        ushort4 v1 = ((const ushort4*)(hs + (size_t)sA[1] * ODIM2))[lane];
        ushort4 v2 = ((const ushort4*)(hs + (size_t)sA[2] * ODIM2))[lane];
        ushort4 v3 = ((const ushort4*)(hs + (size_t)sA[3] * ODIM2))[lane];
        FMA4(c0, v0); FMA4(c1, v1); FMA4(c2, v2); FMA4(c3, v3);
        j += 4;
    }
    for (; j < end; j++) {
        int s = csr[j];
        float c = dinv[s];
        ushort4 v = ((const ushort4*)(hs + (size_t)s * ODIM2))[lane];
        FMA4(c, v);
    }

    float l0 = __shfl(a0, lane | 32);
    float l1 = __shfl(a1, lane | 32);
    float l2 = __shfl(a2, lane | 32);
    float l3 = __shfl(a3, lane | 32);

    if (lane < 32) {
        int c = lane * 4;
        float4 bm = *(const float4*)(bmu + c);
        float4 bl = *(const float4*)(bls + c);
        f32x4 o;
        o[0] = dn * a0 + bm.x + ep[0] * expf(fminf(dn * l0 + bl.x, MAX_LOGSTD));
        o[1] = dn * a1 + bm.y + ep[1] * expf(fminf(dn * l1 + bl.y, MAX_LOGSTD));
        o[2] = dn * a2 + bm.z + ep[2] * expf(fminf(dn * l2 + bl.z, MAX_LOGSTD));
        o[3] = dn * a3 + bm.w + ep[3] * expf(fminf(dn * l3 + bl.w, MAX_LOGSTD));
        __builtin_nontemporal_store(o, (f32x4*)(z + (size_t)n * OUT_DIM + c));
    }
}

extern "C" void kernel_launch(void* const* d_in, const int* in_sizes, int n_in,
                              void* d_out, int out_size, void* d_ws, size_t ws_size,
                              hipStream_t stream) {
    const float* x   = (const float*)d_in[0];
    const int*   ei  = (const int*)  d_in[1];
    const float* Wmu = (const float*)d_in[2];
    const float* bmu = (const float*)d_in[3];
    const float* Wls = (const float*)d_in[4];
    const float* bls = (const float*)d_in[5];
    const float* eps = (const float*)d_in[6];
    float* z = (float*)d_out;

    char* ws = (char*)d_ws;
    size_t off = 0;
    auto alloc = [&](size_t bytes) {
        void* p = ws + off;
        off += (bytes + 255) & ~(size_t)255;
        return p;
    };
    int*   pos  = (int*)  alloc((size_t)N_NODES * 4);         // becomes degree
    float* dinv = (float*)alloc((size_t)N_NODES * 4);
    int*   csr  = (int*)  alloc((size_t)N_NODES * CAP * 4);   // 12.8 MB buckets
    unsigned short* hs = (unsigned short*)alloc((size_t)N_NODES * ODIM2 * 2);
    unsigned short* Wp = (unsigned short*)alloc((size_t)65536 * 2);

    hipMemsetAsync(pos, 0, N_NODES * sizeof(int), stream);

    k_wconv <<<32,                       256, 0, stream>>>(Wmu, Wls, Wp);
    k_fused <<<FILL_BLOCKS + GEMM_TILES, 256, 0, stream>>>(ei, pos, csr, x, Wp, hs);
    k_dinv  <<<NBLK,                     256, 0, stream>>>(pos, dinv);
    k_gather<<<N_NODES / 4,              256, 0, stream>>>(pos, csr, dinv, hs,
                                                           eps, bmu, bls, z);
}

// Round 18
// 119.895 us; speedup vs baseline: 1.0349x; 1.0349x over previous
//
#include <hip/hip_runtime.h>
#include <hip/hip_bf16.h>

#define N_NODES 50000
#define IN_DIM 256
#define OUT_DIM 128
#define ODIM2 256        // mu(128) + logstd(128) concatenated
#define NEDGE 800000
#define MAX_LOGSTD 10.0f
#define CAP 64           // bucket capacity; P(Poisson(16) > 64) ~ 1e-18/node
#define FILL_BLOCKS 1563 // ceil((NEDGE/2)/256), 2 edges/thread
#define GEMM_TILES 1563  // ceil(N_NODES/32), 32-row tiles

typedef short bf16x8 __attribute__((ext_vector_type(8)));
typedef float f32x4  __attribute__((ext_vector_type(4)));
typedef int   i32x4  __attribute__((ext_vector_type(4)));

__device__ __forceinline__ float b2f(unsigned short u) {
    union { unsigned int i; float f; } v; v.i = ((unsigned int)u) << 16; return v.f;
}
__device__ __forceinline__ unsigned short f2b(float f) {
    union { float f; unsigned int i; } v; v.f = f;
    unsigned int x = v.i;
    unsigned int r = (x + 0x7fffu + ((x >> 16) & 1u)) >> 16;
    return (unsigned short)r;
}
__device__ __forceinline__ bool edges_are_i64(const int* raw) {
    bool is64 = true;
    #pragma unroll
    for (int i = 0; i < 8; i++) if (raw[2 * i + 1] != 0) is64 = false;
    return is64;
}

// Pack concat(Wmu,Wls) [256x256] f32 -> B-fragment-ordered bf16.
__global__ void k_wconv(const float* __restrict__ Wmu, const float* __restrict__ Wls,
                        unsigned short* __restrict__ Wp) {
    int i = blockIdx.x * blockDim.x + threadIdx.x;   // 8192 threads
    int lane = i & 63;
    int kk   = (i >> 6) & 7;
    int tile = i >> 9;
    int k0 = kk * 32 + (lane >> 4) * 8;
    int n  = tile * 16 + (lane & 15);
    const float* W = (n < 128) ? (Wmu + n) : (Wls + (n - 128));
    unsigned short o[8];
    #pragma unroll
    for (int j = 0; j < 8; j++) o[j] = f2b(W[(size_t)(k0 + j) * OUT_DIM]);
    ushort4 lo = { o[0], o[1], o[2], o[3] };
    ushort4 hi = { o[4], o[5], o[6], o[7] };
    *(ushort4*)(Wp + (size_t)i * 8)     = lo;
    *(ushort4*)(Wp + (size_t)i * 8 + 4) = hi;
}

// HETEROGENEOUS kernel, roles interleaved by block parity so atomic-latency
// fill waves and MFMA gemm waves coexist on every CU from t=0.
// even blocks: bucket-scatter 2 edges/thread. odd blocks: 32-row MFMA tile
// (16KB LDS) writing UNSCALED h. launch_bounds(256,3): no spill (VGPR 84).
__global__ __launch_bounds__(256, 3) void k_fused(
    const int* __restrict__ raw, int* __restrict__ pos, int* __restrict__ csr,
    const float* __restrict__ x, const unsigned short* __restrict__ Wp,
    unsigned short* __restrict__ h)
{
    __shared__ unsigned short xs[32 * 256];   // 16 KB (gemm path), swizzled
    const int tid = threadIdx.x;

    if ((blockIdx.x & 1) == 0) {
        // ---- fill: 2 edges/thread, bucket csr[d*CAP + p] = s ----
        bool is64 = edges_are_i64(raw);
        int e2 = (blockIdx.x >> 1) * 256 + tid;   // edge-pair index
        if (e2 < NEDGE / 2) {
            int s0, s1, d0, d1;
            if (is64) {
                int4 sv = *(const int4*)(raw + 4 * e2);
                int4 dv = *(const int4*)(raw + 2 * NEDGE + 4 * e2);
                s0 = sv.x; s1 = sv.z; d0 = dv.x; d1 = dv.z;
            } else {
                int2 sv = *(const int2*)(raw + 2 * e2);
                int2 dv = *(const int2*)(raw + NEDGE + 2 * e2);
                s0 = sv.x; s1 = sv.y; d0 = dv.x; d1 = dv.y;
            }
            int p0 = atomicAdd(&pos[d0], 1);
            int p1 = atomicAdd(&pos[d1], 1);
            csr[d0 * CAP + p0] = s0;
            csr[d1 * CAP + p1] = s1;
        }
        return;
    }

    // ---- gemm: 32-row tile, 4 waves, B fragments register-resident ----
    const int lane = tid & 63;
    const int w    = tid >> 6;
    const int row0 = (blockIdx.x >> 1) * 32;

    bf16x8 breg[4][8];
    #pragma unroll
    for (int t = 0; t < 4; t++)
        #pragma unroll
        for (int kk = 0; kk < 8; kk++)
            breg[t][kk] = ((const bf16x8*)Wp)[((4 * w + t) * 8 + kk) * 64 + lane];

    #pragma unroll
    for (int i = 0; i < 8; i++) {
        int f   = i * 256 + tid;
        int row = f >> 6;
        int c4  = f & 63;
        int grow = row0 + row;
        float4 v = make_float4(0.f, 0.f, 0.f, 0.f);
        if (grow < N_NODES) v = *(const float4*)(x + (size_t)grow * IN_DIM + c4 * 4);
        ushort4 b = { f2b(v.x), f2b(v.y), f2b(v.z), f2b(v.w) };
        unsigned int byte = (unsigned)(row * 512 + c4 * 8);
        byte ^= (unsigned)((row & 7) << 4);
        *(ushort4*)((char*)xs + byte) = b;
    }
    __syncthreads();

    #pragma unroll
    for (int sub = 0; sub < 2; sub++) {
        const int arow = sub * 16 + (lane & 15);
        const unsigned int abase = (unsigned)(arow * 512 + (lane >> 4) * 16);
        const unsigned int axor  = (unsigned)((arow & 7) << 4);

        bf16x8 a[8];
        #pragma unroll
        for (int kk = 0; kk < 8; kk++)
            a[kk] = *(const bf16x8*)((const char*)xs + ((abase + kk * 64) ^ axor));

        f32x4 acc[4];
        #pragma unroll
        for (int t = 0; t < 4; t++) acc[t] = (f32x4){0.f, 0.f, 0.f, 0.f};

        #pragma unroll
        for (int kk = 0; kk < 8; kk++)
            #pragma unroll
            for (int t = 0; t < 4; t++)
                acc[t] = __builtin_amdgcn_mfma_f32_16x16x32_bf16(a[kk], breg[t][kk],
                                                                 acc[t], 0, 0, 0);

        // C/D layout: col=lane&15, row=(lane>>4)*4+reg. UNSCALED store.
        const int rbase = row0 + sub * 16 + (lane >> 4) * 4;
        const int cl = lane & 15;
        #pragma unroll
        for (int t = 0; t < 4; t++) {
            int col = (4 * w + t) * 16 + cl;
            #pragma unroll
            for (int r = 0; r < 4; r++) {
                int row = rbase + r;
                if (row < N_NODES)
                    h[(size_t)row * ODIM2 + col] = f2b(acc[t][r]);
            }
        }
    }
}

#define NTI4(p) __builtin_nontemporal_load((const i32x4*)(p))
#define FMA4(c, v) { a0 = fmaf(c, b2f((v).x), a0); a1 = fmaf(c, b2f((v).y), a1); \
                     a2 = fmaf(c, b2f((v).z), a2); a3 = fmaf(c, b2f((v).w), a3); }

// Wave-per-node pull gather, 8 edges in flight. Per-edge normalization inline:
// a += rsqrt(deg_s+1)*h[s]; out = dn*(dn*h[n] + sum) with dn = rsqrt(deg_n+1).
// (R17 measured: dinv-precompute saves 2 us in-kernel but costs 6 us dispatch;
// inline rsqrt is net-better. Gather is fabric-bound at ~3.4 TB/s regardless.)
__global__ __launch_bounds__(256) void k_gather(
    const int* __restrict__ pos, const int* __restrict__ csr,
    const unsigned short* __restrict__ hs, const float* __restrict__ eps,
    const float* __restrict__ bmu, const float* __restrict__ bls,
    float* __restrict__ z)
{
    const int tid  = threadIdx.x;
    const int n    = blockIdx.x * 4 + (tid >> 6);
    const int lane = tid & 63;
    const int deg  = pos[n];
    const float dn = rsqrtf((float)deg + 1.0f);

    // hoist streaming epilogue input (NT: don't pollute L2)
    f32x4 ep = {0.f, 0.f, 0.f, 0.f};
    if (lane < 32)
        ep = __builtin_nontemporal_load((const f32x4*)(eps + (size_t)n * OUT_DIM + lane * 4));

    float a0, a1, a2, a3;
    {   // self-loop seed: dn * h[n]  (outer dn applied at the end)
        ushort4 v = ((const ushort4*)(hs + (size_t)n * ODIM2))[lane];
        a0 = dn * b2f(v.x); a1 = dn * b2f(v.y);
        a2 = dn * b2f(v.z); a3 = dn * b2f(v.w);
    }

    const int beg = n * CAP;                       // 4-aligned by construction
    const int end = beg + deg;
    int j = beg;
    for (; j + 8 <= end; j += 8) {                 // 8 gathers in flight
        i32x4 sA = NTI4(csr + j);
        i32x4 sB = NTI4(csr + j + 4);
        float c0 = rsqrtf((float)pos[sA[0]] + 1.0f);
        float c1 = rsqrtf((float)pos[sA[1]] + 1.0f);
        float c2 = rsqrtf((float)pos[sA[2]] + 1.0f);
        float c3 = rsqrtf((float)pos[sA[3]] + 1.0f);
        float c4 = rsqrtf((float)pos[sB[0]] + 1.0f);
        float c5 = rsqrtf((float)pos[sB[1]] + 1.0f);
        float c6 = rsqrtf((float)pos[sB[2]] + 1.0f);
        float c7 = rsqrtf((float)pos[sB[3]] + 1.0f);
        ushort4 v0 = ((const ushort4*)(hs + (size_t)sA[0] * ODIM2))[lane];
        ushort4 v1 = ((const ushort4*)(hs + (size_t)sA[1] * ODIM2))[lane];
        ushort4 v2 = ((const ushort4*)(hs + (size_t)sA[2] * ODIM2))[lane];
        ushort4 v3 = ((const ushort4*)(hs + (size_t)sA[3] * ODIM2))[lane];
        ushort4 v4 = ((const ushort4*)(hs + (size_t)sB[0] * ODIM2))[lane];
        ushort4 v5 = ((const ushort4*)(hs + (size_t)sB[1] * ODIM2))[lane];
        ushort4 v6 = ((const ushort4*)(hs + (size_t)sB[2] * ODIM2))[lane];
        ushort4 v7 = ((const ushort4*)(hs + (size_t)sB[3] * ODIM2))[lane];
        FMA4(c0, v0); FMA4(c1, v1); FMA4(c2, v2); FMA4(c3, v3);
        FMA4(c4, v4); FMA4(c5, v5); FMA4(c6, v6); FMA4(c7, v7);
    }
    if (j + 4 <= end) {
        i32x4 sA = NTI4(csr + j);
        float c0 = rsqrtf((float)pos[sA[0]] + 1.0f);
        float c1 = rsqrtf((float)pos[sA[1]] + 1.0f);
        float c2 = rsqrtf((float)pos[sA[2]] + 1.0f);
        float c3 = rsqrtf((float)pos[sA[3]] + 1.0f);
        ushort4 v0 = ((const ushort4*)(hs + (size_t)sA[0] * ODIM2))[lane];
        ushort4 v1 = ((const ushort4*)(hs + (size_t)sA[1] * ODIM2))[lane];
        ushort4 v2 = ((const ushort4*)(hs + (size_t)sA[2] * ODIM2))[lane];
        ushort4 v3 = ((const ushort4*)(hs + (size_t)sA[3] * ODIM2))[lane];
        FMA4(c0, v0); FMA4(c1, v1); FMA4(c2, v2); FMA4(c3, v3);
        j += 4;
    }
    for (; j < end; j++) {
        int s = csr[j];
        float c = rsqrtf((float)pos[s] + 1.0f);
        ushort4 v = ((const ushort4*)(hs + (size_t)s * ODIM2))[lane];
        FMA4(c, v);
    }

    float l0 = __shfl(a0, lane | 32);
    float l1 = __shfl(a1, lane | 32);
    float l2 = __shfl(a2, lane | 32);
    float l3 = __shfl(a3, lane | 32);

    if (lane < 32) {
        int c = lane * 4;
        float4 bm = *(const float4*)(bmu + c);
        float4 bl = *(const float4*)(bls + c);
        f32x4 o;
        o[0] = dn * a0 + bm.x + ep[0] * expf(fminf(dn * l0 + bl.x, MAX_LOGSTD));
        o[1] = dn * a1 + bm.y + ep[1] * expf(fminf(dn * l1 + bl.y, MAX_LOGSTD));
        o[2] = dn * a2 + bm.z + ep[2] * expf(fminf(dn * l2 + bl.z, MAX_LOGSTD));
        o[3] = dn * a3 + bm.w + ep[3] * expf(fminf(dn * l3 + bl.w, MAX_LOGSTD));
        __builtin_nontemporal_store(o, (f32x4*)(z + (size_t)n * OUT_DIM + c));
    }
}

extern "C" void kernel_launch(void* const* d_in, const int* in_sizes, int n_in,
                              void* d_out, int out_size, void* d_ws, size_t ws_size,
                              hipStream_t stream) {
    const float* x   = (const float*)d_in[0];
    const int*   ei  = (const int*)  d_in[1];
    const float* Wmu = (const float*)d_in[2];
    const float* bmu = (const float*)d_in[3];
    const float* Wls = (const float*)d_in[4];
    const float* bls = (const float*)d_in[5];
    const float* eps = (const float*)d_in[6];
    float* z = (float*)d_out;

    char* ws = (char*)d_ws;
    size_t off = 0;
    auto alloc = [&](size_t bytes) {
        void* p = ws + off;
        off += (bytes + 255) & ~(size_t)255;
        return p;
    };
    int* pos = (int*)alloc((size_t)N_NODES * 4);              // becomes degree
    int* csr = (int*)alloc((size_t)N_NODES * CAP * 4);        // 12.8 MB buckets
    unsigned short* hs = (unsigned short*)alloc((size_t)N_NODES * ODIM2 * 2);
    unsigned short* Wp = (unsigned short*)alloc((size_t)65536 * 2);

    hipMemsetAsync(pos, 0, N_NODES * sizeof(int), stream);

    k_wconv <<<32,                       256, 0, stream>>>(Wmu, Wls, Wp);
    k_fused <<<FILL_BLOCKS + GEMM_TILES, 256, 0, stream>>>(ei, pos, csr, x, Wp, hs);
    k_gather<<<N_NODES / 4,              256, 0, stream>>>(pos, csr, hs,
                                                           eps, bmu, bls, z);
}